// Round 6
// baseline (148.682 us; speedup 1.0000x reference)
//
#include <hip/hip_runtime.h>
#include <math.h>

#define N_TOK 8192
#define DDIM  768
#define NEXP  16
#define WPAD  17   // Wl row stride in floats: c-stride 816 = 16 (mod 32)
                   // -> wave's 64 b128 slots tile all 32 banks = conflict-free

typedef float f32x4 __attribute__((ext_vector_type(4)));

// Output layout (floats), concatenated in reference return order:
// y[N,D] | soft_avg[16] | hard_avg[16] | s_concat[N,16] | scalar 0
#define SOFT_OFF (N_TOK*DDIM)
#define HARD_OFF (SOFT_OFF + NEXP)
#define S_OFF    (HARD_OFF + NEXP)
#define SCAL_OFF (S_OFF + N_TOK*NEXP)

// d_ws layout: table[8192] of {e0,e1,w0,w1} (f32x4) at ws[0].
// Fully overwritten by gate before combine reads it (stream order), no
// atomics anywhere -> no zeroing kernel needed, bitwise deterministic.

__device__ __forceinline__ void fma4(f32x4& a, float s, f32x4 w) {
  a.x = fmaf(s, w.x, a.x);
  a.y = fmaf(s, w.y, a.y);
  a.z = fmaf(s, w.z, a.z);
  a.w = fmaf(s, w.w, a.w);
}

__device__ __forceinline__ float xred(float v) {
  // reduce across the 16 d-chunks: c lives in lane bits 2..5
  v += __shfl_xor(v, 4);
  v += __shfl_xor(v, 8);
  v += __shfl_xor(v, 16);
  v += __shfl_xor(v, 32);
  return v;
}

__device__ __forceinline__ void finish_token(
    int n, f32x4 av, int lane, float* __restrict__ out,
    f32x4* __restrict__ table) {
  // gather all 16 logits (lane q<4 holds expert quad 4q..4q+3); uniform result
  float v[16];
  #pragma unroll
  for (int q = 0; q < 4; ++q) {
    v[q*4+0] = __shfl(av.x, q);
    v[q*4+1] = __shfl(av.y, q);
    v[q*4+2] = __shfl(av.z, q);
    v[q*4+3] = __shfl(av.w, q);
  }
  // top-2, stable (strict > keeps lowest index on ties, matching lax.top_k)
  float v0 = -INFINITY, v1 = -INFINITY;
  int e0 = 0, e1 = 0;
  #pragma unroll
  for (int j = 0; j < 16; ++j) {
    float val = v[j];
    if (val > v0) { v1 = v0; e1 = e0; v0 = val; e0 = j; }
    else if (val > v1) { v1 = val; e1 = j; }
  }
  float t1  = expf(v1 - v0);
  float inv = 1.0f / (1.0f + t1);
  float w0  = inv;
  float w1  = t1 * inv;
  if (lane == 0) {
    f32x4 rec;
    rec.x = __int_as_float(e0); rec.y = __int_as_float(e1);
    rec.z = w0; rec.w = w1;
    table[n] = rec;
  }
  if (lane < NEXP) {
    float g  = (lane == e0) ? w0 : ((lane == e1) ? w1 : 0.0f);
    out[S_OFF + (size_t)n*NEXP + lane] = (g >= 1e-5f) ? 0.0f : 1.0f;
  }
}

extern "C" __global__ __launch_bounds__(256) void gate_kernel(
    const float* __restrict__ x, const float* __restrict__ W,
    const float* __restrict__ bias, float* __restrict__ out,
    float* __restrict__ ws) {
  __shared__ float Wl[DDIM*WPAD];   // 52.2 KB
  f32x4* table = (f32x4*)ws;
  int tid = threadIdx.x;
  for (int idx = tid; idx < DDIM*NEXP; idx += 256) {
    int e = idx / DDIM;             // coalesced global read of W[idx]
    int d = idx - e*DDIM;
    Wl[d*WPAD + e] = W[idx];        // transpose into padded LDS
  }
  __syncthreads();

  int wave = tid >> 6;
  int lane = tid & 63;
  int e4 = lane & 3;                // expert quad 0..3
  int c  = lane >> 2;               // d-chunk 0..15 (48 d's each)
  f32x4 bq = ((const f32x4*)bias)[e4];

  #pragma unroll
  for (int p = 0; p < 2; ++p) {
    int pairi = (blockIdx.x*4 + wave) + p*2048;   // 512 blocks * 4 waves * 2
    int n0 = pairi*2, n1 = n0 + 1;                // 2 tokens share W reads
    const float* x0p = x + (size_t)n0*DDIM + c*48;
    const float* x1p = x + (size_t)n1*DDIM + c*48;
    const float* wbase = &Wl[(c*48)*WPAD + 4*e4];
    f32x4 a0 = {0.f,0.f,0.f,0.f};
    f32x4 a1 = {0.f,0.f,0.f,0.f};
    #pragma unroll
    for (int m = 0; m < 12; ++m) {
      f32x4 xv0 = *(const f32x4*)(x0p + 4*m);
      f32x4 xv1 = *(const f32x4*)(x1p + 4*m);
      const float* wb = wbase + m*4*WPAD;
      f32x4 wq0 = *(const f32x4*)(wb);
      f32x4 wq1 = *(const f32x4*)(wb + WPAD);
      f32x4 wq2 = *(const f32x4*)(wb + 2*WPAD);
      f32x4 wq3 = *(const f32x4*)(wb + 3*WPAD);
      fma4(a0, xv0.x, wq0); fma4(a0, xv0.y, wq1);
      fma4(a0, xv0.z, wq2); fma4(a0, xv0.w, wq3);
      fma4(a1, xv1.x, wq0); fma4(a1, xv1.y, wq1);
      fma4(a1, xv1.z, wq2); fma4(a1, xv1.w, wq3);
    }
    a0.x = xred(a0.x); a0.y = xred(a0.y); a0.z = xred(a0.z); a0.w = xred(a0.w);
    a1.x = xred(a1.x); a1.y = xred(a1.y); a1.z = xred(a1.z); a1.w = xred(a1.w);
    a0.x += bq.x; a0.y += bq.y; a0.z += bq.z; a0.w += bq.w;
    a1.x += bq.x; a1.y += bq.y; a1.z += bq.z; a1.w += bq.w;
    finish_token(n0, a0, lane, out, table);
    finish_token(n1, a1, lane, out, table);
  }
}

// Persistent combine: 2048 blocks (8/CU), 4 tokens each, no barriers in the
// stream path -> next-token loads issue while current token reduces; no
// block launch/retire churn between tokens.
extern "C" __global__ __launch_bounds__(256) void combine_kernel(
    const float* __restrict__ f, const float* __restrict__ ws,
    float* __restrict__ out) {
  const int tid = threadIdx.x;
  const f32x4* table = (const f32x4*)ws;
  __shared__ float red[4][2*NEXP];

  if (blockIdx.x == 0) {
    // derive soft/hard averages from the table (gate done: stream-ordered).
    // wave wv covers tokens [wv*2048, wv*2048+2048); lane = e + 16h, h = the
    // 4-token sub-stream -> pure register accumulation, ~2us, overlapped.
    const int wv = tid >> 6, lane = tid & 63;
    const int e = lane & 15, h = lane >> 4;
    float asoft = 0.f, ahard = 0.f;
    for (int i = 0; i < 512; ++i) {
      f32x4 rec = table[wv*2048 + 4*i + h];
      int e0 = __float_as_int(rec.x);
      int e1 = __float_as_int(rec.y);
      float g = (e == e0) ? rec.z : ((e == e1) ? rec.w : 0.0f);
      asoft += g;
      ahard += (g >= 1e-5f) ? 1.0f : 0.0f;
    }
    asoft += __shfl_xor(asoft, 16); asoft += __shfl_xor(asoft, 32);
    ahard += __shfl_xor(ahard, 16); ahard += __shfl_xor(ahard, 32);
    if (lane < NEXP) { red[wv][e] = asoft; red[wv][NEXP + e] = ahard; }
    __syncthreads();               // uniform within block 0 only: legal
    if (tid < 2*NEXP) {
      float s = red[0][tid] + red[1][tid] + red[2][tid] + red[3][tid];
      out[SOFT_OFF + tid] = s * (1.0f/N_TOK);
    }
    if (tid == 0) out[SCAL_OFF] = 0.0f;
  }

  const int jg = (tid & 3) * 4;    // this thread's expert sub-quad
  #pragma unroll 1                 // keep VGPR bounded; stream stays hot
  for (int t = 0; t < 4; ++t) {
    const int n = blockIdx.x*4 + t;
    f32x4 rec = table[n];          // L2-hot
    int e0 = __float_as_int(rec.x);
    int e1 = __float_as_int(rec.y);
    float w0 = rec.z, w1 = rec.w;
    float gx = (jg+0 == e0) ? w0 : ((jg+0 == e1) ? w1 : 0.0f);
    float gy = (jg+1 == e0) ? w0 : ((jg+1 == e1) ? w1 : 0.0f);
    float gz = (jg+2 == e0) ? w0 : ((jg+2 == e1) ? w1 : 0.0f);
    float gw = (jg+3 == e0) ? w0 : ((jg+3 == e1) ? w1 : 0.0f);
    const f32x4* fp = (const f32x4*)(f + (size_t)n * (DDIM*NEXP));
    float* yr = out + (size_t)n * DDIM;
    #pragma unroll
    for (int k = 0; k < 12; ++k) {
      int q = tid + 256*k;
      f32x4 v = fp[q];             // 1KiB fully-coalesced per wave instr
      float p = v.x*gx + v.y*gy + v.z*gz + v.w*gw;
      p += __shfl_xor(p, 1);       // 4 consecutive lanes hold one d
      p += __shfl_xor(p, 2);
      if ((tid & 3) == 0) yr[q >> 2] = p;   // 16 lanes -> contiguous 64B
    }
  }
}

extern "C" void kernel_launch(void* const* d_in, const int* in_sizes, int n_in,
                              void* d_out, int out_size, void* d_ws, size_t ws_size,
                              hipStream_t stream) {
  const float* f = (const float*)d_in[0];   // [N, D, E]
  const float* x = (const float*)d_in[1];   // [N, D]
  const float* W = (const float*)d_in[2];   // [E, D]
  const float* b = (const float*)d_in[3];   // [E]
  float* out = (float*)d_out;
  float* ws  = (float*)d_ws;

  hipLaunchKernelGGL(gate_kernel, dim3(512), dim3(256), 0, stream,
                     x, W, b, out, ws);
  hipLaunchKernelGGL(combine_kernel, dim3(2048), dim3(256), 0, stream,
                     f, ws, out);
}

// Round 7
// 118.734 us; speedup vs baseline: 1.2522x; 1.2522x over previous
//
#include <hip/hip_runtime.h>
#include <math.h>

#define N_TOK 8192
#define DDIM  768
#define NEXP  16
#define WPAD  17   // Wl row stride in floats: c-stride 816 = 16 (mod 32)
                   // -> wave's 64 b128 slots tile all 32 banks = conflict-free

typedef float f32x4 __attribute__((ext_vector_type(4)));

// Output layout (floats), concatenated in reference return order:
// y[N,D] | soft_avg[16] | hard_avg[16] | s_concat[N,16] | scalar 0
#define SOFT_OFF (N_TOK*DDIM)
#define HARD_OFF (SOFT_OFF + NEXP)
#define S_OFF    (HARD_OFF + NEXP)
#define SCAL_OFF (S_OFF + N_TOK*NEXP)

// d_ws layout: table[8192] of {e0,e1,w0,w1} (f32x4) at ws[0].
// Fully overwritten by gate before combine reads it (stream order), no
// atomics anywhere -> no zeroing kernel needed, bitwise deterministic.

__device__ __forceinline__ void fma4(f32x4& a, float s, f32x4 w) {
  a.x = fmaf(s, w.x, a.x);
  a.y = fmaf(s, w.y, a.y);
  a.z = fmaf(s, w.z, a.z);
  a.w = fmaf(s, w.w, a.w);
}

__device__ __forceinline__ float xred(float v) {
  // reduce across the 16 d-chunks: c lives in lane bits 2..5
  v += __shfl_xor(v, 4);
  v += __shfl_xor(v, 8);
  v += __shfl_xor(v, 16);
  v += __shfl_xor(v, 32);
  return v;
}

__device__ __forceinline__ void finish_token(
    int n, f32x4 av, int lane, float* __restrict__ out,
    f32x4* __restrict__ table) {
  // gather all 16 logits (lane q<4 holds expert quad 4q..4q+3); uniform result
  float v[16];
  #pragma unroll
  for (int q = 0; q < 4; ++q) {
    v[q*4+0] = __shfl(av.x, q);
    v[q*4+1] = __shfl(av.y, q);
    v[q*4+2] = __shfl(av.z, q);
    v[q*4+3] = __shfl(av.w, q);
  }
  // top-2, stable (strict > keeps lowest index on ties, matching lax.top_k)
  float v0 = -INFINITY, v1 = -INFINITY;
  int e0 = 0, e1 = 0;
  #pragma unroll
  for (int j = 0; j < 16; ++j) {
    float val = v[j];
    if (val > v0) { v1 = v0; e1 = e0; v0 = val; e0 = j; }
    else if (val > v1) { v1 = val; e1 = j; }
  }
  float t1  = expf(v1 - v0);
  float inv = 1.0f / (1.0f + t1);
  float w0  = inv;
  float w1  = t1 * inv;
  if (lane == 0) {
    f32x4 rec;
    rec.x = __int_as_float(e0); rec.y = __int_as_float(e1);
    rec.z = w0; rec.w = w1;
    table[n] = rec;
  }
  if (lane < NEXP) {
    float g  = (lane == e0) ? w0 : ((lane == e1) ? w1 : 0.0f);
    out[S_OFF + (size_t)n*NEXP + lane] = (g >= 1e-5f) ? 0.0f : 1.0f;
  }
}

extern "C" __global__ __launch_bounds__(256) void gate_kernel(
    const float* __restrict__ x, const float* __restrict__ W,
    const float* __restrict__ bias, float* __restrict__ out,
    float* __restrict__ ws) {
  __shared__ float Wl[DDIM*WPAD];   // 52.2 KB
  f32x4* table = (f32x4*)ws;
  int tid = threadIdx.x;
  for (int idx = tid; idx < DDIM*NEXP; idx += 256) {
    int e = idx / DDIM;             // coalesced global read of W[idx]
    int d = idx - e*DDIM;
    Wl[d*WPAD + e] = W[idx];        // transpose into padded LDS
  }
  __syncthreads();

  int wave = tid >> 6;
  int lane = tid & 63;
  int e4 = lane & 3;                // expert quad 0..3
  int c  = lane >> 2;               // d-chunk 0..15 (48 d's each)
  f32x4 bq = ((const f32x4*)bias)[e4];

  #pragma unroll
  for (int p = 0; p < 2; ++p) {
    int pairi = (blockIdx.x*4 + wave) + p*2048;   // 512 blocks * 4 waves * 2
    int n0 = pairi*2, n1 = n0 + 1;                // 2 tokens share W reads
    const float* x0p = x + (size_t)n0*DDIM + c*48;
    const float* x1p = x + (size_t)n1*DDIM + c*48;
    const float* wbase = &Wl[(c*48)*WPAD + 4*e4];
    f32x4 a0 = {0.f,0.f,0.f,0.f};
    f32x4 a1 = {0.f,0.f,0.f,0.f};
    #pragma unroll
    for (int m = 0; m < 12; ++m) {
      f32x4 xv0 = *(const f32x4*)(x0p + 4*m);
      f32x4 xv1 = *(const f32x4*)(x1p + 4*m);
      const float* wb = wbase + m*4*WPAD;
      f32x4 wq0 = *(const f32x4*)(wb);
      f32x4 wq1 = *(const f32x4*)(wb + WPAD);
      f32x4 wq2 = *(const f32x4*)(wb + 2*WPAD);
      f32x4 wq3 = *(const f32x4*)(wb + 3*WPAD);
      fma4(a0, xv0.x, wq0); fma4(a0, xv0.y, wq1);
      fma4(a0, xv0.z, wq2); fma4(a0, xv0.w, wq3);
      fma4(a1, xv1.x, wq0); fma4(a1, xv1.y, wq1);
      fma4(a1, xv1.z, wq2); fma4(a1, xv1.w, wq3);
    }
    a0.x = xred(a0.x); a0.y = xred(a0.y); a0.z = xred(a0.z); a0.w = xred(a0.w);
    a1.x = xred(a1.x); a1.y = xred(a1.y); a1.z = xred(a1.z); a1.w = xred(a1.w);
    a0.x += bq.x; a0.y += bq.y; a0.z += bq.z; a0.w += bq.w;
    a1.x += bq.x; a1.y += bq.y; a1.z += bq.z; a1.w += bq.w;
    finish_token(n0, a0, lane, out, table);
    finish_token(n1, a1, lane, out, table);
  }
}

// Line-per-lane combine: one token per block; thread t owns d = t, t+256,
// t+512 -> loads the full 64B line (all 16 experts) for each of its d's,
// dots it against the uniform g quads in registers, one scalar store.
// No shuffles, no LDS, no barriers in the stream path: post-load tail is
// ~50 VALU ops, so the wave's loads stay outstanding nearly all the time.
extern "C" __global__ __launch_bounds__(256) void combine_kernel(
    const float* __restrict__ f, const float* __restrict__ ws,
    float* __restrict__ out) {
  const int tid = threadIdx.x;
  const int n   = blockIdx.x;
  const f32x4* table = (const f32x4*)ws;

  f32x4 rec = table[n];            // L2-hot
  const int e0 = __float_as_int(rec.x);
  const int e1 = __float_as_int(rec.y);
  const float w0 = rec.z, w1 = rec.w;
  f32x4 g[4];                      // uniform per block; 2 nonzeros among 16
  #pragma unroll
  for (int j = 0; j < 4; ++j) {
    g[j].x = (4*j+0 == e0) ? w0 : ((4*j+0 == e1) ? w1 : 0.0f);
    g[j].y = (4*j+1 == e0) ? w0 : ((4*j+1 == e1) ? w1 : 0.0f);
    g[j].z = (4*j+2 == e0) ? w0 : ((4*j+2 == e1) ? w1 : 0.0f);
    g[j].w = (4*j+3 == e0) ? w0 : ((4*j+3 == e1) ? w1 : 0.0f);
  }

  const f32x4* fp = (const f32x4*)(f + (size_t)n * (DDIM*NEXP));
  float* yr = out + (size_t)n * DDIM;
  float acc[3];
  f32x4 q[3][4];
  #pragma unroll
  for (int i = 0; i < 3; ++i) {    // issue all 12 loads up front
    const f32x4* lp = fp + (tid + 256*i)*4;
    q[i][0] = lp[0]; q[i][1] = lp[1]; q[i][2] = lp[2]; q[i][3] = lp[3];
  }
  #pragma unroll
  for (int i = 0; i < 3; ++i) {
    float a = 0.f;
    #pragma unroll
    for (int j = 0; j < 4; ++j) {
      a = fmaf(q[i][j].x, g[j].x, a);
      a = fmaf(q[i][j].y, g[j].y, a);
      a = fmaf(q[i][j].z, g[j].z, a);
      a = fmaf(q[i][j].w, g[j].w, a);
    }
    acc[i] = a;
  }
  #pragma unroll
  for (int i = 0; i < 3; ++i)
    yr[tid + 256*i] = acc[i];      // 256 consecutive floats: 1KB dense/wave

  // block 0: derive soft/hard averages from the table, after its stream so
  // the extra ~8KB scan overlaps other blocks' streaming.
  if (n == 0) {
    __shared__ float red[4][2*NEXP];
    const int wv = tid >> 6, lane = tid & 63;
    const int e = lane & 15, h = lane >> 4;
    float asoft = 0.f, ahard = 0.f;
    for (int i = 0; i < 512; ++i) {
      f32x4 r = table[wv*2048 + 4*i + h];
      int a0 = __float_as_int(r.x);
      int a1 = __float_as_int(r.y);
      float gg = (e == a0) ? r.z : ((e == a1) ? r.w : 0.0f);
      asoft += gg;
      ahard += (gg >= 1e-5f) ? 1.0f : 0.0f;
    }
    asoft += __shfl_xor(asoft, 16); asoft += __shfl_xor(asoft, 32);
    ahard += __shfl_xor(ahard, 16); ahard += __shfl_xor(ahard, 32);
    if (lane < NEXP) { red[wv][e] = asoft; red[wv][NEXP + e] = ahard; }
    __syncthreads();               // uniform within block 0 only: legal
    if (tid < 2*NEXP) {
      float s = red[0][tid] + red[1][tid] + red[2][tid] + red[3][tid];
      out[SOFT_OFF + tid] = s * (1.0f/N_TOK);
    }
    if (tid == 0) out[SCAL_OFF] = 0.0f;
  }
}

extern "C" void kernel_launch(void* const* d_in, const int* in_sizes, int n_in,
                              void* d_out, int out_size, void* d_ws, size_t ws_size,
                              hipStream_t stream) {
  const float* f = (const float*)d_in[0];   // [N, D, E]
  const float* x = (const float*)d_in[1];   // [N, D]
  const float* W = (const float*)d_in[2];   // [E, D]
  const float* b = (const float*)d_in[3];   // [E]
  float* out = (float*)d_out;
  float* ws  = (float*)d_ws;

  hipLaunchKernelGGL(gate_kernel, dim3(512), dim3(256), 0, stream,
                     x, W, b, out, ws);
  hipLaunchKernelGGL(combine_kernel, dim3(N_TOK), dim3(256), 0, stream,
                     f, ws, out);
}